// Round 6
// baseline (58.890 us; speedup 1.0000x reference)
//
#include <hip/hip_runtime.h>
#include <hip/hip_fp16.h>

#define NV 5
#define NB 4
#define NJ 15
#define HMW 128
#define HMH 128
#define P_TOTAL (64 * 64 * 64)        // 262144 points per batch
#define HM_PLANE (HMH * HMW)          // 16384 quads per plane
#define CUBES_ELEMS ((size_t)NB * NJ * P_TOTAL)
#define N_PLANES (NV * NB * NJ)       // 300
#define QUAD_BYTES ((size_t)N_PLANES * HM_PLANE * 8)   // 39,321,600

struct __align__(8) H4 { __half2 r0, r1; };   // 2x2 corner quad, 4 x f16
struct F2 { float x, y; };

// ---- pre-pass: pack 2x2 corner quads, micro-tiled 2x4 pixels per 64B line ----
// quad index within plane: qi = ((ty*32+tx)<<3) | (wy<<2) | wx
//   where ty=y>>1, tx=x>>2, wy=y&1, wx=x&3
__global__ __launch_bounds__(256) void build_quads_tiled(
    const float* __restrict__ hm, H4* __restrict__ q)
{
    const int idx = blockIdx.x * 256 + threadIdx.x;    // plane*16384 + qi
    const int qi  = idx & (HM_PLANE - 1);
    const int pl  = idx >> 14;
    const int within = qi & 7;
    const int tile   = qi >> 3;
    const int x = (tile & 31) * 4 + (within & 3);
    const int y = (tile >> 5) * 2 + (within >> 2);

    const float* img = hm + (size_t)pl * HM_PLANE;
    const int x1 = (x < 127) ? x + 1 : 127;
    const int y1 = (y < 127) ? y + 1 : 127;
    const float v00 = img[y  * HMW + x], v01 = img[y  * HMW + x1];
    const float v10 = img[y1 * HMW + x], v11 = img[y1 * HMW + x1];
    H4 h;
    h.r0 = __floats2half2_rn(v00, v01);
    h.r1 = __floats2half2_rn(v10, v11);
    q[idx] = h;
}

// ---- main: 4x4x4 wave tiles, branch-free 75-gather stream, LDS-transposed stores
__global__ __launch_bounds__(256) void project_layer_tiled(
    const H4*  __restrict__ quads,     // (NV*NB*NJ, 16384) micro-tiled quads
    const float* __restrict__ projM,   // (NV, NB, 3, 4)
    const float* __restrict__ center,  // (NB, 3)
    const int*   __restrict__ gsize,   // scalar
    float* __restrict__ out)           // cubes | grids
{
    __shared__ float xpose[NJ + 3][256];               // 18 KB

    const int blk = blockIdx.x;
    const int b   = blk >> 10;                         // 1024 blocks per batch
    const int ib  = (blk >> 6) & 15;                   // block footprint (4,4,16)
    const int jb  = (blk >> 2) & 15;
    const int kb  = blk & 3;

    const int t  = threadIdx.x;
    const int w  = t >> 6;                             // wave -> k-quarter
    const int l  = t & 63;
    const int di = l >> 4;                             // wave tile (4,4,4)
    const int dj = (l >> 2) & 3;
    const int dk = l & 3;

    const int gi = ib * 4 + di;
    const int gj = jb * 4 + dj;
    const int gk = kb * 16 + w * 4 + dk;

    const float gs   = (float)gsize[0];
    const float half = gs * 0.5f;
    const float step = gs / 63.0f;

    const float cx = center[b * 3 + 0];
    const float cy = center[b * 3 + 1];
    const float cz = center[b * 3 + 2];

    // numpy linspace forces the endpoint exactly
    const float gx = ((gi == 63) ? half : fmaf((float)gi, step, -half)) + cx;
    const float gy = ((gj == 63) ? half : fmaf((float)gj, step, -half)) + cy;
    const float gz = ((gk == 63) ? half : fmaf((float)gk, step, -half)) + cz;

    // ---- phase 1: branch-free per-view weights + offsets ----
    float vw00[NV], vw01[NV], vw10[NV], vw11[NV];
    int   voff[NV];
    float cnt = 0.0f;

#pragma unroll
    for (int n = 0; n < NV; ++n) {
        const float* M = projM + ((size_t)(n * NB + b)) * 12;
        // homog = [x, z, y, 1]
        const float px = M[0] * gx + M[1] * gz + M[2]  * gy + M[3];
        const float py = M[4] * gx + M[5] * gz + M[6]  * gy + M[7];
        const float pz = M[8] * gx + M[9] * gz + M[10] * gy + M[11];

        // exact division: the inb boundary tests must match the reference
        const float u = px / pz;
        const float v = py / pz;

        // NaN/inf comparisons are false -> view gets zero weights (exact no-op)
        const bool inb = (u >= 0.0f) && (v >= 0.0f) && (u < 512.0f) && (v < 512.0f);

        // ix == u*0.25 (reference's clips are no-ops when in-bounds)
        const float ix = u * 0.25f;                  // in [0, 128) when inb
        const float iy = v * 0.25f;

        const float x0f = floorf(ix);
        const float y0f = floorf(iy);
        const float wx1 = ix - x0f, wx0 = 1.0f - wx1;
        const float wy1 = iy - y0f, wy0 = 1.0f - wy1;

        const int x0 = (int)x0f;                     // 0..127 when inb
        const int y0 = (int)y0f;

        // fold edge validity into weights (exact zeros, reference corner order)
        const float wx1v = (x0 < 127) ? wx1 : 0.0f;
        const float wy1v = (y0 < 127) ? wy1 : 0.0f;

        // select (not multiply): NaN-safe zeroing for invalid views
        vw00[n] = inb ? (wx0  * wy0 ) : 0.0f;
        vw01[n] = inb ? (wx1v * wy0 ) : 0.0f;
        vw10[n] = inb ? (wx0  * wy1v) : 0.0f;
        vw11[n] = inb ? (wx1v * wy1v) : 0.0f;

        const int qi = (((y0 >> 1) * 32 + (x0 >> 2)) << 3) | ((y0 & 1) << 2) | (x0 & 3);
        voff[n] = inb ? qi : 0;
        cnt += inb ? 1.0f : 0.0f;
    }

    // ---- phase 2: 75 independent gathers + FMA, no branches ----
    float num[NJ];
#pragma unroll
    for (int j = 0; j < NJ; ++j) num[j] = 0.0f;

#pragma unroll
    for (int n = 0; n < NV; ++n) {
        const H4* qb = quads + ((size_t)(n * NB + b) * NJ) * HM_PLANE + voff[n];
        const float w00 = vw00[n], w01 = vw01[n], w10 = vw10[n], w11 = vw11[n];
#pragma unroll
        for (int j = 0; j < NJ; ++j) {
            const H4 qd = qb[(size_t)j * HM_PLANE];
            const float2 f0 = __half22float2(qd.r0);  // (e00, e01)
            const float2 f1 = __half22float2(qd.r1);  // (e10, e11)
            // reference corner order: (x0,y0) (x1,y0) (x0,y1) (x1,y1)
            num[j] += w00 * f0.x + w01 * f0.y + w10 * f1.x + w11 * f1.y;
        }
    }

    const float den = cnt + 1e-6f;
    const float r   = 1.0f / den;

    // ---- LDS transpose: tiled lanes -> linear footprint ----
    const int f = di * 64 + dj * 16 + w * 4 + dk;
    const int s = f ^ (((f >> 6) & 3) << 2);           // break 8-way write conflict
#pragma unroll
    for (int j = 0; j < NJ; ++j)
        xpose[j][s] = fminf(fmaxf(num[j] * r, 0.0f), 1.0f);
    xpose[NJ + 0][s] = gx;
    xpose[NJ + 1][s] = gy;
    xpose[NJ + 2][s] = gz;
    __syncthreads();

    // ---- coalesced store phase ----
    const int k2 = t & 15, j2 = (t >> 4) & 3, i2 = t >> 6;
    const int s2 = t ^ (((t >> 6) & 3) << 2);          // same swizzle on read
    const int p  = (ib * 4 + i2) * 4096 + (jb * 4 + j2) * 64 + kb * 16 + k2;

    {
        float* cb = out + (size_t)b * NJ * P_TOTAL + p;
#pragma unroll
        for (int j = 0; j < NJ; ++j)
            __builtin_nontemporal_store(xpose[j][s2], &cb[(size_t)j * P_TOTAL]);
    }
    {
        float* go = out + CUBES_ELEMS + ((size_t)b * P_TOTAL + p) * 3;
        __builtin_nontemporal_store(xpose[NJ + 0][s2], &go[0]);
        __builtin_nontemporal_store(xpose[NJ + 1][s2], &go[1]);
        __builtin_nontemporal_store(xpose[NJ + 2][s2], &go[2]);
    }
}

// ---------------- fallback (proven R1 kernel, used if ws too small) ----------
__global__ __launch_bounds__(256) void project_layer_fallback(
    const float* __restrict__ hm,
    const float* __restrict__ projM,
    const float* __restrict__ center,
    const int*   __restrict__ gsize,
    float* __restrict__ out)
{
    const int blk = blockIdx.x;
    const int b   = blk >> 10;
    const int p   = ((blk & 1023) << 8) | threadIdx.x;
    const int gi  = p >> 12;
    const int gj  = (p >> 6) & 63;
    const int gk  = p & 63;

    const float gs   = (float)gsize[0];
    const float half = gs * 0.5f;
    const float step = gs / 63.0f;

    const float cx = center[b * 3 + 0];
    const float cy = center[b * 3 + 1];
    const float cz = center[b * 3 + 2];

    const float gx = ((gi == 63) ? half : fmaf((float)gi, step, -half)) + cx;
    const float gy = ((gj == 63) ? half : fmaf((float)gj, step, -half)) + cy;
    const float gz = ((gk == 63) ? half : fmaf((float)gk, step, -half)) + cz;

    float num[NJ];
#pragma unroll
    for (int j = 0; j < NJ; ++j) num[j] = 0.0f;
    float cnt = 0.0f;

    for (int n = 0; n < NV; ++n) {
        const float* M = projM + ((size_t)(n * NB + b)) * 12;
        const float px = M[0] * gx + M[1] * gz + M[2]  * gy + M[3];
        const float py = M[4] * gx + M[5] * gz + M[6]  * gy + M[7];
        const float pz = M[8] * gx + M[9] * gz + M[10] * gy + M[11];
        const float u = px / pz;
        const float v = py / pz;
        const bool inb = (u >= 0.0f) && (v >= 0.0f) && (u < 512.0f) && (v < 512.0f);
        if (!inb) continue;
        cnt += 1.0f;
        const float ix = u * 0.25f;
        const float iy = v * 0.25f;
        const float x0f = floorf(ix);
        const float y0f = floorf(iy);
        const float wx1 = ix - x0f, wx0 = 1.0f - wx1;
        const float wy1 = iy - y0f, wy0 = 1.0f - wy1;
        const int x0 = (int)x0f;
        const int y0 = (int)y0f;
        const bool  xe = (x0 == 127);
        const float wA = xe ? 0.0f : wx0;
        const float wB = xe ? wx0  : wx1;
        const float wy1v = (y0 <= 126) ? wy1 : 0.0f;
        const float wA0 = wA * wy0;
        const float wB0 = wB * wy0;
        const float wA1 = wA * wy1v;
        const float wB1 = wB * wy1v;
        const int xb  = xe ? 126 : x0;
        const int yr1 = (y0 <= 126) ? (y0 + 1) : 127;
        const int o0  = y0  * HMW + xb;
        const int o1  = yr1 * HMW + xb;
        const float* img = hm + ((size_t)(n * NB + b) * NJ) * HM_PLANE;
#pragma unroll
        for (int j = 0; j < NJ; ++j) {
            const float* ij = img + (size_t)j * HM_PLANE;
            const F2 r0 = *(const F2*)(ij + o0);
            const F2 r1 = *(const F2*)(ij + o1);
            num[j] += wA0 * r0.x + wB0 * r0.y + wA1 * r1.x + wB1 * r1.y;
        }
    }

    const float den = cnt + 1e-6f;
    const float r   = 1.0f / den;
    {
        float* cb = out + (size_t)b * NJ * P_TOTAL + p;
#pragma unroll
        for (int j = 0; j < NJ; ++j) {
            const float c = num[j] * r;
            __builtin_nontemporal_store(fminf(fmaxf(c, 0.0f), 1.0f),
                                        &cb[(size_t)j * P_TOTAL]);
        }
    }
    {
        float* go = out + CUBES_ELEMS + ((size_t)b * P_TOTAL + p) * 3;
        __builtin_nontemporal_store(gx, &go[0]);
        __builtin_nontemporal_store(gy, &go[1]);
        __builtin_nontemporal_store(gz, &go[2]);
    }
}

extern "C" void kernel_launch(void* const* d_in, const int* in_sizes, int n_in,
                              void* d_out, int out_size, void* d_ws, size_t ws_size,
                              hipStream_t stream) {
    const float* hm     = (const float*)d_in[0];
    const float* projM  = (const float*)d_in[1];
    const float* center = (const float*)d_in[2];
    const int*   gsize  = (const int*)d_in[3];
    float* out = (float*)d_out;

    const int blocks = NB * 1024;                    // 4096

    if (ws_size >= QUAD_BYTES) {
        H4* quads = (H4*)d_ws;
        const int qthreads = N_PLANES * HM_PLANE;    // 4,915,200
        build_quads_tiled<<<qthreads / 256, 256, 0, stream>>>(hm, quads);
        project_layer_tiled<<<blocks, 256, 0, stream>>>(quads, projM, center, gsize, out);
    } else {
        project_layer_fallback<<<blocks, 256, 0, stream>>>(hm, projM, center, gsize, out);
    }
}

// Round 7
// 41.956 us; speedup vs baseline: 1.4036x; 1.4036x over previous
//
#include <hip/hip_runtime.h>
#include <hip/hip_fp16.h>

#define NV 5
#define NB 4
#define NJ 15
#define HMW 128
#define HMH 128
#define P_TOTAL (64 * 64 * 64)        // 262144 points per batch
#define HM_PLANE (HMH * HMW)          // 16384 quads per plane
#define CUBES_ELEMS ((size_t)NB * NJ * P_TOTAL)
#define N_PLANES (NV * NB * NJ)       // 300
#define QUAD_BYTES ((size_t)N_PLANES * HM_PLANE * 8)   // 39,321,600

struct __align__(8) H4 { __half2 r0, r1; };   // 2x2 corner quad, 4 x f16
struct F2 { float x, y; };

// ---- pre-pass: pack 2x2 corner quads, micro-tiled 2x4 pixels per 64B line ----
// quad index within plane: qi = ((ty*32+tx)<<3) | (wy<<2) | wx
//   where ty=y>>1, tx=x>>2, wy=y&1, wx=x&3
__global__ __launch_bounds__(256) void build_quads_tiled(
    const float* __restrict__ hm, H4* __restrict__ q)
{
    const int idx = blockIdx.x * 256 + threadIdx.x;    // plane*16384 + qi
    const int qi  = idx & (HM_PLANE - 1);
    const int pl  = idx >> 14;
    const int within = qi & 7;
    const int tile   = qi >> 3;
    const int x = (tile & 31) * 4 + (within & 3);
    const int y = (tile >> 5) * 2 + (within >> 2);

    const float* img = hm + (size_t)pl * HM_PLANE;
    const int x1 = (x < 127) ? x + 1 : 127;
    const int y1 = (y < 127) ? y + 1 : 127;
    const float v00 = img[y  * HMW + x], v01 = img[y  * HMW + x1];
    const float v10 = img[y1 * HMW + x], v11 = img[y1 * HMW + x1];
    H4 h;
    h.r0 = __floats2half2_rn(v00, v01);
    h.r1 = __floats2half2_rn(v10, v11);
    q[idx] = h;
}

// ---- main (R4 structure): 4x4x4 wave tiles, branchy wave-coherent view loop,
// ---- micro-tiled quad gather, LDS-transposed coalesced stores
__global__ __launch_bounds__(256) void project_layer_tiled(
    const H4*  __restrict__ quads,     // (NV*NB*NJ, 16384) micro-tiled quads
    const float* __restrict__ projM,   // (NV, NB, 3, 4)
    const float* __restrict__ center,  // (NB, 3)
    const int*   __restrict__ gsize,   // scalar
    float* __restrict__ out)           // cubes | grids
{
    __shared__ float xpose[NJ + 3][256];               // 18 KB

    const int blk = blockIdx.x;
    const int b   = blk >> 10;                         // 1024 blocks per batch
    const int ib  = (blk >> 6) & 15;                   // block footprint (4,4,16)
    const int jb  = (blk >> 2) & 15;
    const int kb  = blk & 3;

    const int t  = threadIdx.x;
    const int w  = t >> 6;                             // wave -> k-quarter
    const int l  = t & 63;
    const int di = l >> 4;                             // wave tile (4,4,4)
    const int dj = (l >> 2) & 3;
    const int dk = l & 3;

    const int gi = ib * 4 + di;
    const int gj = jb * 4 + dj;
    const int gk = kb * 16 + w * 4 + dk;

    const float gs   = (float)gsize[0];
    const float half = gs * 0.5f;
    const float step = gs / 63.0f;

    const float cx = center[b * 3 + 0];
    const float cy = center[b * 3 + 1];
    const float cz = center[b * 3 + 2];

    // numpy linspace forces the endpoint exactly
    const float gx = ((gi == 63) ? half : fmaf((float)gi, step, -half)) + cx;
    const float gy = ((gj == 63) ? half : fmaf((float)gj, step, -half)) + cy;
    const float gz = ((gk == 63) ? half : fmaf((float)gk, step, -half)) + cz;

    float num[NJ];
#pragma unroll
    for (int j = 0; j < NJ; ++j) num[j] = 0.0f;
    float cnt = 0.0f;

    for (int n = 0; n < NV; ++n) {
        const float* M = projM + ((size_t)(n * NB + b)) * 12;
        // homog = [x, z, y, 1]
        const float px = M[0] * gx + M[1] * gz + M[2]  * gy + M[3];
        const float py = M[4] * gx + M[5] * gz + M[6]  * gy + M[7];
        const float pz = M[8] * gx + M[9] * gz + M[10] * gy + M[11];

        // exact division: the inb boundary tests must match the reference
        const float u = px / pz;
        const float v = py / pz;

        // NaN/inf comparisons are false -> view skipped, matches reference.
        // Wave-coherent skip: ~73% of (tile,view) pairs are fully OOB.
        const bool inb = (u >= 0.0f) && (v >= 0.0f) && (u < 512.0f) && (v < 512.0f);
        if (!inb) continue;

        cnt += 1.0f;

        // ix == u*0.25 (reference's clips are no-ops when in-bounds)
        const float ix = u * 0.25f;                  // in [0, 128)
        const float iy = v * 0.25f;

        const float x0f = floorf(ix);
        const float y0f = floorf(iy);
        const float wx1 = ix - x0f, wx0 = 1.0f - wx1;
        const float wy1 = iy - y0f, wy0 = 1.0f - wy1;

        const int x0 = (int)x0f;                     // 0..127
        const int y0 = (int)y0f;

        // fold edge validity into weights (exact zeros, reference corner order)
        const float wx1v = (x0 < 127) ? wx1 : 0.0f;
        const float wy1v = (y0 < 127) ? wy1 : 0.0f;

        const float w00 = wx0  * wy0;
        const float w01 = wx1v * wy0;
        const float w10 = wx0  * wy1v;
        const float w11 = wx1v * wy1v;

        // micro-tiled quad index
        const int qi = (((y0 >> 1) * 32 + (x0 >> 2)) << 3) | ((y0 & 1) << 2) | (x0 & 3);
        const H4* qb = quads + ((size_t)(n * NB + b) * NJ) * HM_PLANE + qi;
#pragma unroll
        for (int j = 0; j < NJ; ++j) {
            const H4 qd = qb[(size_t)j * HM_PLANE];
            const float2 f0 = __half22float2(qd.r0);  // (e00, e01)
            const float2 f1 = __half22float2(qd.r1);  // (e10, e11)
            // reference corner order: (x0,y0) (x1,y0) (x0,y1) (x1,y1)
            num[j] += w00 * f0.x + w01 * f0.y + w10 * f1.x + w11 * f1.y;
        }
    }

    const float den = cnt + 1e-6f;
    const float r   = 1.0f / den;

    // ---- LDS transpose: tiled lanes -> linear footprint ----
    const int f = di * 64 + dj * 16 + w * 4 + dk;
    const int s = f ^ (((f >> 6) & 3) << 2);           // break 8-way write conflict
#pragma unroll
    for (int j = 0; j < NJ; ++j)
        xpose[j][s] = fminf(fmaxf(num[j] * r, 0.0f), 1.0f);
    xpose[NJ + 0][s] = gx;
    xpose[NJ + 1][s] = gy;
    xpose[NJ + 2][s] = gz;
    __syncthreads();

    // ---- coalesced store phase ----
    const int k2 = t & 15, j2 = (t >> 4) & 3, i2 = t >> 6;
    const int s2 = t ^ (((t >> 6) & 3) << 2);          // same swizzle on read
    const int p  = (ib * 4 + i2) * 4096 + (jb * 4 + j2) * 64 + kb * 16 + k2;

    {
        float* cb = out + (size_t)b * NJ * P_TOTAL + p;
#pragma unroll
        for (int j = 0; j < NJ; ++j)
            __builtin_nontemporal_store(xpose[j][s2], &cb[(size_t)j * P_TOTAL]);
    }
    {
        float* go = out + CUBES_ELEMS + ((size_t)b * P_TOTAL + p) * 3;
        __builtin_nontemporal_store(xpose[NJ + 0][s2], &go[0]);
        __builtin_nontemporal_store(xpose[NJ + 1][s2], &go[1]);
        __builtin_nontemporal_store(xpose[NJ + 2][s2], &go[2]);
    }
}

// ---------------- fallback (proven R1 kernel, used if ws too small) ----------
__global__ __launch_bounds__(256) void project_layer_fallback(
    const float* __restrict__ hm,
    const float* __restrict__ projM,
    const float* __restrict__ center,
    const int*   __restrict__ gsize,
    float* __restrict__ out)
{
    const int blk = blockIdx.x;
    const int b   = blk >> 10;
    const int p   = ((blk & 1023) << 8) | threadIdx.x;
    const int gi  = p >> 12;
    const int gj  = (p >> 6) & 63;
    const int gk  = p & 63;

    const float gs   = (float)gsize[0];
    const float half = gs * 0.5f;
    const float step = gs / 63.0f;

    const float cx = center[b * 3 + 0];
    const float cy = center[b * 3 + 1];
    const float cz = center[b * 3 + 2];

    const float gx = ((gi == 63) ? half : fmaf((float)gi, step, -half)) + cx;
    const float gy = ((gj == 63) ? half : fmaf((float)gj, step, -half)) + cy;
    const float gz = ((gk == 63) ? half : fmaf((float)gk, step, -half)) + cz;

    float num[NJ];
#pragma unroll
    for (int j = 0; j < NJ; ++j) num[j] = 0.0f;
    float cnt = 0.0f;

    for (int n = 0; n < NV; ++n) {
        const float* M = projM + ((size_t)(n * NB + b)) * 12;
        const float px = M[0] * gx + M[1] * gz + M[2]  * gy + M[3];
        const float py = M[4] * gx + M[5] * gz + M[6]  * gy + M[7];
        const float pz = M[8] * gx + M[9] * gz + M[10] * gy + M[11];
        const float u = px / pz;
        const float v = py / pz;
        const bool inb = (u >= 0.0f) && (v >= 0.0f) && (u < 512.0f) && (v < 512.0f);
        if (!inb) continue;
        cnt += 1.0f;
        const float ix = u * 0.25f;
        const float iy = v * 0.25f;
        const float x0f = floorf(ix);
        const float y0f = floorf(iy);
        const float wx1 = ix - x0f, wx0 = 1.0f - wx1;
        const float wy1 = iy - y0f, wy0 = 1.0f - wy1;
        const int x0 = (int)x0f;
        const int y0 = (int)y0f;
        const bool  xe = (x0 == 127);
        const float wA = xe ? 0.0f : wx0;
        const float wB = xe ? wx0  : wx1;
        const float wy1v = (y0 <= 126) ? wy1 : 0.0f;
        const float wA0 = wA * wy0;
        const float wB0 = wB * wy0;
        const float wA1 = wA * wy1v;
        const float wB1 = wB * wy1v;
        const int xb  = xe ? 126 : x0;
        const int yr1 = (y0 <= 126) ? (y0 + 1) : 127;
        const int o0  = y0  * HMW + xb;
        const int o1  = yr1 * HMW + xb;
        const float* img = hm + ((size_t)(n * NB + b) * NJ) * HM_PLANE;
#pragma unroll
        for (int j = 0; j < NJ; ++j) {
            const float* ij = img + (size_t)j * HM_PLANE;
            const F2 r0 = *(const F2*)(ij + o0);
            const F2 r1 = *(const F2*)(ij + o1);
            num[j] += wA0 * r0.x + wB0 * r0.y + wA1 * r1.x + wB1 * r1.y;
        }
    }

    const float den = cnt + 1e-6f;
    const float r   = 1.0f / den;
    {
        float* cb = out + (size_t)b * NJ * P_TOTAL + p;
#pragma unroll
        for (int j = 0; j < NJ; ++j) {
            const float c = num[j] * r;
            __builtin_nontemporal_store(fminf(fmaxf(c, 0.0f), 1.0f),
                                        &cb[(size_t)j * P_TOTAL]);
        }
    }
    {
        float* go = out + CUBES_ELEMS + ((size_t)b * P_TOTAL + p) * 3;
        __builtin_nontemporal_store(gx, &go[0]);
        __builtin_nontemporal_store(gy, &go[1]);
        __builtin_nontemporal_store(gz, &go[2]);
    }
}

extern "C" void kernel_launch(void* const* d_in, const int* in_sizes, int n_in,
                              void* d_out, int out_size, void* d_ws, size_t ws_size,
                              hipStream_t stream) {
    const float* hm     = (const float*)d_in[0];
    const float* projM  = (const float*)d_in[1];
    const float* center = (const float*)d_in[2];
    const int*   gsize  = (const int*)d_in[3];
    float* out = (float*)d_out;

    const int blocks = NB * 1024;                    // 4096

    if (ws_size >= QUAD_BYTES) {
        H4* quads = (H4*)d_ws;
        const int qthreads = N_PLANES * HM_PLANE;    // 4,915,200
        build_quads_tiled<<<qthreads / 256, 256, 0, stream>>>(hm, quads);
        project_layer_tiled<<<blocks, 256, 0, stream>>>(quads, projM, center, gsize, out);
    } else {
        project_layer_fallback<<<blocks, 256, 0, stream>>>(hm, projM, center, gsize, out);
    }
}